// Round 12
// baseline (233.724 us; speedup 1.0000x reference)
//
#include <hip/hip_runtime.h>

#define TOKENS 8192
#define IN_F   4096
#define OUT_F  4096

#define BM 256
#define BN 256
#define BK 64
#define NT (IN_F / BK)   // 64 K-tiles

typedef __attribute__((ext_vector_type(4))) float  f32x4;
typedef __attribute__((ext_vector_type(4))) int    i32x4;

// ---------------------------------------------------------------------------
// quant_x: per-token symmetric i8 quantization -> FRAGMENT-ORDER layout
// (r11-verified). A-granule (kt, g) = 1 KiB at aq[(kt*512 + g)*1024 + lane*16]:
//   lane l (lr=l&15, cg=l>>4) holds row g*16+lr, k = kt*64 + cg*16 .. +16.
// ---------------------------------------------------------------------------
__global__ __launch_bounds__(256) void quant_x_kernel(const float* __restrict__ x,
                                                      signed char* __restrict__ aq,
                                                      float* __restrict__ dx) {
    const int g   = blockIdx.x;          // 0..511
    const int tid = threadIdx.x;
    const float* xr0 = x + (size_t)g * 16 * IN_F;

    const int r1 = tid >> 4;
    const int c1 = tid & 15;
    float m = 0.f;
    const float* p = xr0 + (size_t)r1 * IN_F + c1 * 4;
    for (int s = 0; s < 64; ++s) {
        f32x4 v = *(const f32x4*)(p + s * 64);
        m = fmaxf(fmaxf(fabsf(v[0]), fabsf(v[1])),
                  fmaxf(fmaxf(fabsf(v[2]), fabsf(v[3])), m));
    }
#pragma unroll
    for (int off = 1; off < 16; off <<= 1) m = fmaxf(m, __shfl_xor(m, off));
    __shared__ float sm[16];
    if (c1 == 0) sm[r1] = m;
    __syncthreads();
    if (tid < 16) dx[g * 16 + tid] = sm[tid] * (1.0f / 127.0f);

    const int lane = tid & 63, w = tid >> 6;
    const int lr = lane & 15, cg = lane >> 4;
    const float inv = 127.0f / sm[lr];
    const float* xp = xr0 + (size_t)lr * IN_F;
    signed char* outb = aq + (((size_t)(w * 16) * 512 + g) << 10) + lane * 16;

    for (int s = 0; s < 16; ++s) {
        const int kt = w * 16 + s;
        const f32x4* src = (const f32x4*)(xp + kt * 64 + cg * 16);
        i32x4 o;
#pragma unroll
        for (int k = 0; k < 4; ++k) {
            f32x4 v = src[k];
            int pk = 0;
#pragma unroll
            for (int j = 0; j < 4; ++j) {
                int q = (int)rintf(v[j] * inv);
                pk |= (q & 0xff) << (8 * j);
            }
            o[k] = pk;
        }
        *(i32x4*)(outb + ((size_t)s * 512 << 10)) = o;
    }
}

// ---------------------------------------------------------------------------
// quant_w: ternary -> i8 in fragment order (r10/r11-verified).
// Granule (bn, kt, g) = 1 KiB at wq[((bn*64+kt)*16+g)*1024 + lane*16].
// ---------------------------------------------------------------------------
__global__ __launch_bounds__(256) void quant_w_kernel(const int* __restrict__ tern,
                                                      const float* __restrict__ scales,
                                                      signed char* __restrict__ wq,
                                                      float* __restrict__ dw) {
    const int o0   = blockIdx.x << 4;
    const int tid  = threadIdx.x;
    const int lane = tid & 63;
    const int lr   = lane & 15;
    const int lg   = lane >> 4;
    const int kt0  = tid >> 6;

    const int o = o0 + lr;
    const float* sr = scales + o * 32;
    float smax = 0.f;
#pragma unroll
    for (int g = 0; g < 32; ++g) smax = fmaxf(smax, sr[g]);
    const float rs = 127.0f / smax;
    if (tid < 16) dw[o0 + tid] = smax * (1.0f / 127.0f);

    const int bn  = o0 >> 8;
    const int g16 = (o0 >> 4) & 15;
    signed char* outb = wq + ((size_t)((bn * 64) * 16 + g16) << 10) + lane * 16;

#pragma unroll
    for (int i = 0; i < 16; ++i) {
        const int kt = kt0 * 16 + i;
        const int c  = kt * 4 + lg;
        const int iq = (int)rintf(sr[c >> 3] * rs);
        const i32x4* tp = (const i32x4*)(tern + (size_t)o * IN_F + c * 16);
        i32x4 w4;
#pragma unroll
        for (int k = 0; k < 4; ++k) {
            i32x4 tt = tp[k];
            int pk = 0;
#pragma unroll
            for (int j = 0; j < 4; ++j) pk |= ((tt[j] * iq) & 0xff) << (8 * j);
            w4[k] = pk;
        }
        *(i32x4*)(outb + ((size_t)(kt * 16) << 10)) = w4;
    }
}

// ---------------------------------------------------------------------------
// C = (xq . wq^T) * dx[m] * dw[n], i8 MFMA 16x16x64, i32 acc.
// r12 HYBRID: A via LDS (4-way wave sharing; frag-order granules; stride-1
// conflict-free ds_read_b128; REG-STAGED global->reg->ds_write so the
// compiler tracks every wait — no inline asm, no global_load_lds);
// B direct global->reg frag-order (r11), double-buffered bA/bB (rule #20).
// 256x256 tile, 8 waves (2M x 4N), per-wave 128x64, acc 128 AGPR.
// Per tile: issue A(t+1)->regs | 8 ds_read A-frags | 4 B-loads(t+1) |
//   32 MFMA | sync | ds_write A(t+1)->As[buf^1] | sync.
// Pipes: LDS 80 KB/tile (~940cy) < MFMA (1306cy); A-stg and B loads have
// ~1400cy issue-to-use slack. Hazards: a[]-reads consumed by MFMA before
// sync1 => lgkm-complete before As[buf] rewritten (iter t+1 after sync2).
// ---------------------------------------------------------------------------

#define MFMA_ALL(AF, BF)                                                       \
  do {                                                                         \
    __builtin_amdgcn_s_setprio(1);                                             \
    _Pragma("unroll") for (int mi = 0; mi < 8; ++mi)                           \
      _Pragma("unroll") for (int ni = 0; ni < 4; ++ni)                         \
          acc[mi][ni] = __builtin_amdgcn_mfma_i32_16x16x64_i8(                 \
              AF[mi], BF[ni], acc[mi][ni], 0, 0, 0);                           \
    __builtin_amdgcn_s_setprio(0);                                             \
  } while (0)

#define LOADB(BF, T)                                                           \
  do {                                                                         \
    _Pragma("unroll") for (int ni = 0; ni < 4; ++ni)                           \
        BF[ni] = *(const i32x4*)(bB + (((size_t)(T) * 16 + ni) << 10));        \
  } while (0)

#define BODY(T, BC, BNX)                                                       \
  do {                                                                         \
    if ((T) + 1 < NT) {                                                        \
      const signed char* s_ = aSrc + ((size_t)((T) + 1) * 512 << 10);          \
      sA0 = *(const i32x4*)s_;                                                 \
      sA1 = *(const i32x4*)(s_ + 16);                                          \
    }                                                                          \
    const int base_ = ((T) & 1) * 16384;                                       \
    _Pragma("unroll") for (int mi = 0; mi < 8; ++mi)                           \
        a[mi] = *(const i32x4*)&As[base_ + ((wm * 8 + mi) << 10) + lane * 16]; \
    if ((T) + 1 < NT) LOADB(BNX, (T) + 1);                                     \
    MFMA_ALL(a, BC);                                                           \
    __syncthreads();                                                           \
    if ((T) + 1 < NT) {                                                        \
      *(i32x4*)&As[(base_ ^ 16384) + tid * 32]      = sA0;                     \
      *(i32x4*)&As[(base_ ^ 16384) + tid * 32 + 16] = sA1;                     \
    }                                                                          \
    __syncthreads();                                                           \
  } while (0)

__global__ __launch_bounds__(512, 2) void gemm_i8_kernel(
        const signed char* __restrict__ A,
        const signed char* __restrict__ B,
        const float* __restrict__ dX,
        const float* __restrict__ dW,
        float* __restrict__ C) {
    __shared__ __align__(16) signed char As[2 * 16384];

    const int tid  = threadIdx.x;
    const int wave = tid >> 6;
    const int lane = tid & 63;
    const int wm   = wave >> 2;        // 0-1
    const int wn   = wave & 3;         // 0-3
    const int lg   = lane >> 4;        // 0-3
    const int lr   = lane & 15;        // 0-15

    // XCD swizzle, bn-grouped: XCD x owns bn {2x, 2x+1} (B panels L2-resident)
    const int bid = blockIdx.x;
    const int bn  = ((bid & 7) << 1) | (bid >> 8);   // 0..15
    const int bm  = (bid >> 3) & 31;                 // 0..31

    const size_t a_row0 = (size_t)bm * BM;
    const size_t b_row0 = (size_t)bn * BN;

    // A stage source: block's 16 granules (16 KB) per tile; thread's 32 B.
    const signed char* aSrc = A + (((size_t)(bm * 16)) << 10) + tid * 32;
    // B fragment base: granule (bn, kt=0, g = wn*4 + ni), this lane's 16B.
    const signed char* bB = B + (((size_t)(bn * 64 * 16 + wn * 4)) << 10) + lane * 16;

    i32x4 acc[8][4] = {};
    i32x4 a[8], bA[4], bBuf[4];
    i32x4 sA0, sA1;

    // ---- prologue: tile0 A -> LDS buf0; B(0) -> regs
    sA0 = *(const i32x4*)aSrc;
    sA1 = *(const i32x4*)(aSrc + 16);
    *(i32x4*)&As[tid * 32]      = sA0;
    *(i32x4*)&As[tid * 32 + 16] = sA1;
    LOADB(bA, 0);
    __syncthreads();

    for (int tt = 0; tt < NT; tt += 2) {
        BODY(tt,     bA,   bBuf);
        BODY(tt + 1, bBuf, bA);
    }

    // ---- epilogue: out = acc * dx[row] * dw[col]; C/D col=lane&15, row=lg*4+j
    float dwc[4];
#pragma unroll
    for (int ni = 0; ni < 4; ++ni) dwc[ni] = dW[b_row0 + wn * 64 + ni * 16 + lr];

    float* Cp = C + (a_row0 + wm * 128) * (size_t)OUT_F + b_row0 + wn * 64;
#pragma unroll
    for (int mi = 0; mi < 8; ++mi) {
#pragma unroll
        for (int j = 0; j < 4; ++j) {
            const int r = mi * 16 + lg * 4 + j;
            const float dxr = dX[a_row0 + wm * 128 + r];
#pragma unroll
            for (int ni = 0; ni < 4; ++ni)
                Cp[(size_t)r * OUT_F + ni * 16 + lr] =
                    (float)acc[mi][ni][j] * dxr * dwc[ni];
        }
    }
}

extern "C" void kernel_launch(void* const* d_in, const int* in_sizes, int n_in,
                              void* d_out, int out_size, void* d_ws, size_t ws_size,
                              hipStream_t stream) {
    const float* x      = (const float*)d_in[0];
    const int*   tern   = (const int*)d_in[1];
    const float* scales = (const float*)d_in[2];

    signed char* xq = (signed char*)d_ws;                  // 33.6 MB (frag order)
    signed char* wq = xq + (size_t)TOKENS * IN_F;          // 16.8 MB (frag order)
    float*       dx = (float*)(wq + (size_t)OUT_F * IN_F);
    float*       dw = dx + TOKENS;

    quant_x_kernel<<<TOKENS / 16, 256, 0, stream>>>(x, xq, dx);
    quant_w_kernel<<<OUT_F / 16, 256, 0, stream>>>(tern, scales, wq, dw);

    dim3 grid((TOKENS / BM) * (OUT_F / BN));   // 512
    gemm_i8_kernel<<<grid, 512, 0, stream>>>(xq, wq, dx, dw, (float*)d_out);
}

// Round 13
// 177.723 us; speedup vs baseline: 1.3151x; 1.3151x over previous
//
#include <hip/hip_runtime.h>

#define TOKENS 8192
#define IN_F   4096
#define OUT_F  4096

#define BM 256
#define BN 256
#define BK 128
#define NT (IN_F / BK)   // 32 K-tiles

typedef __attribute__((ext_vector_type(4))) float  f32x4;
typedef __attribute__((ext_vector_type(4))) int    i32x4;

typedef const __attribute__((address_space(1))) void gas_void;
typedef __attribute__((address_space(3))) void las_void;

// ---------------------------------------------------------------------------
// quant_x: per-token symmetric i8 quantization. One block (256 thr) per row.
// ---------------------------------------------------------------------------
__global__ __launch_bounds__(256) void quant_x_kernel(const float* __restrict__ x,
                                                      signed char* __restrict__ xq,
                                                      float* __restrict__ dx) {
    const int row  = blockIdx.x;
    const int tid  = threadIdx.x;
    const int lane = tid & 63;
    const int wv   = tid >> 6;
    const float* xr = x + (size_t)row * IN_F;

    float v[16];
#pragma unroll
    for (int k = 0; k < 4; ++k) {
        f32x4 t = *(const f32x4*)(xr + k * 1024 + tid * 4);
#pragma unroll
        for (int j = 0; j < 4; ++j) v[k * 4 + j] = t[j];
    }
    float m = 0.f;
#pragma unroll
    for (int j = 0; j < 16; ++j) m = fmaxf(m, fabsf(v[j]));
#pragma unroll
    for (int off = 32; off >= 1; off >>= 1) m = fmaxf(m, __shfl_xor(m, off));
    __shared__ float sm[4];
    if (lane == 0) sm[wv] = m;
    __syncthreads();
    m = fmaxf(fmaxf(sm[0], sm[1]), fmaxf(sm[2], sm[3]));

    const float inv = 127.0f / m;
    if (tid == 0) dx[row] = m * (1.0f / 127.0f);

    int* out = (int*)(xq + (size_t)row * IN_F);
#pragma unroll
    for (int k = 0; k < 4; ++k) {
        int p = 0;
#pragma unroll
        for (int j = 0; j < 4; ++j) {
            int q = (int)rintf(v[k * 4 + j] * inv);
            p |= (q & 0xff) << (8 * j);
        }
        out[k * 256 + tid] = p;
    }
}

// ---------------------------------------------------------------------------
// quant_w: per-out-row integer re-scale of ternary weights.
// ---------------------------------------------------------------------------
__global__ __launch_bounds__(256) void quant_w_kernel(const int* __restrict__ tern,
                                                      const float* __restrict__ scales,
                                                      signed char* __restrict__ wq,
                                                      float* __restrict__ dw) {
    const int o   = blockIdx.x;
    const int tid = threadIdx.x;
    const float* sr = scales + o * 32;

    float smax = 0.f;
#pragma unroll
    for (int g = 0; g < 32; ++g) smax = fmaxf(smax, sr[g]);
    if (tid == 0) dw[o] = smax * (1.0f / 127.0f);

    const int g  = tid >> 3;
    const int iq = (int)rintf(sr[g] * (127.0f / smax));

    const i32x4* tp = (const i32x4*)(tern + (size_t)o * IN_F + tid * 16);
    i32x4 out;
#pragma unroll
    for (int k = 0; k < 4; ++k) {
        i32x4 t = tp[k];
        int p = 0;
#pragma unroll
        for (int j = 0; j < 4; ++j) p |= ((t[j] * iq) & 0xff) << (8 * j);
        out[k] = p;
    }
    *(i32x4*)(wq + (size_t)o * IN_F + tid * 16) = out;
}

// ---------------------------------------------------------------------------
// C[M][N] = (xq . wq^T) * dx[m] * dw[n],  i8 MFMA 16x16x64, i32 acc.
// 256x256 tile, BK=128, 8 waves (2M x 4N), per-wave 128x64, acc 128 AGPR.
// r13 = r6 (best, 137us, 42.9% MfmaUtil) + PHASE THROTTLE: the tile is split
// into 4 phases, each {reads for exactly that QUAD + 16 MFMA}, separated by
// PLAIN s_barriers (no sched fences, no lgkm asm — compiler schedules freely
// within phases; barriers only throttle the runtime LDS read burst so the
// FIFO serves ~48 reads/phase instead of ~192/tile, m201's de-burst).
// Correctness never depends on the plain barriers:
//   reads/QUADs may drift across them; the two FENCED barriers (end-P3 =
//   As[buf]-protect after ALL a-reads; end-P4 = staging-visible after
//   vmcnt) are exactly r6's and carry sched_barrier(0) on both sides.
// Phases: P1 rdA0-3(8)+rdB01(4), stage B(t+1)h0, QUAD(0,0) | P2 rdB23(4),
//   stage B(t+1)h1, QUAD(0,2) | P3 rdA4-7(8), QUAD(4,2), FENCED BAR |
//   P4 stage A(t+2)h0+h1, QUAD(4,0), vmcnt(4), FENCED BAR.
// vmcnt audit (FIFO, 8 loads/tile): gate leaves A(t+2)'s 4 in flight,
// drains B(t+1)+older; t=NT-2 -> vmcnt(0); t=NT-1 -> no gate. Prologue:
// tile0 A+B (8 loads) + tile1 A (4); vmcnt(4) drains tile0.
// ---------------------------------------------------------------------------

#define QUAD(MI0, NI0)                                                         \
  do {                                                                         \
    __builtin_amdgcn_s_setprio(1);                                             \
    _Pragma("unroll") for (int mi = 0; mi < 4; ++mi)                           \
      _Pragma("unroll") for (int ni = 0; ni < 2; ++ni)                         \
        _Pragma("unroll") for (int kk = 0; kk < 2; ++kk)                       \
          acc[(MI0)+mi][(NI0)+ni] = __builtin_amdgcn_mfma_i32_16x16x64_i8(     \
              a[(MI0)+mi][kk], b[(NI0)+ni][kk], acc[(MI0)+mi][(NI0)+ni],0,0,0);\
    __builtin_amdgcn_s_setprio(0);                                             \
  } while (0)

__global__ __launch_bounds__(512, 2) void gemm_i8_kernel(
        const signed char* __restrict__ A,
        const signed char* __restrict__ B,
        const float* __restrict__ dX,
        const float* __restrict__ dW,
        float* __restrict__ C) {
    __shared__ __align__(16) signed char As[2 * 256 * 128];
    __shared__ __align__(16) signed char Bs[2 * 256 * 128];

    const int tid  = threadIdx.x;
    const int wave = tid >> 6;
    const int lane = tid & 63;
    const int wm   = wave >> 2;        // 0-1
    const int wn   = wave & 3;         // 0-3
    const int lg   = lane >> 4;        // 0-3
    const int lr   = lane & 15;        // 0-15

    int bid = blockIdx.x;
    bid = (bid & 7) * (512 >> 3) + (bid >> 3);   // XCD swizzle, 512%8==0
    const int bm = bid >> 4;           // 0-31
    const int bn = bid & 15;           // 0-15

    const size_t a_row0 = (size_t)bm * BM;
    const size_t b_row0 = (size_t)bn * BN;

    // stage one half-tile (128 rows x 128 i8 = 16 KiB): 2 loads/thread.
    auto stage_half = [&](int buf, int half, int which, int k0) {
        const signed char* G = which ? B : A;
        const size_t grow0 = (which ? b_row0 : a_row0) + (size_t)half * 128;
        signed char* T = (which ? Bs : As) + buf * 32768 + half * 16384;
#pragma unroll
        for (int i = 0; i < 2; ++i) {
            const int qe    = (i * 512 + tid) * 16;         // byte offset in half
            const int row_h = qe >> 7;                      // 0..127
            const int cswz  = (qe & 127) ^ ((row_h & 7) << 4);
            const signed char* src = G + (grow0 + row_h) * IN_F + k0 + cswz;
            signed char* dst = T + i * 8192 + wave * 1024;  // wave-uniform base
            __builtin_amdgcn_global_load_lds((gas_void*)src, (las_void*)dst, 16, 0, 0);
        }
    };

    i32x4 acc[8][4] = {};
    i32x4 a[8][2], b[4][2];

    const int sw16 = (lr & 7) << 4;
    const int arow = (wm * 128 + lr) * 128;
    const int brow = (wn * 64  + lr) * 128;

    auto rdA = [&](int mi, int base) {
        a[mi][0] = *(const i32x4*)&As[base + arow + mi * 2048 + ((lg * 16) ^ sw16)];
        a[mi][1] = *(const i32x4*)&As[base + arow + mi * 2048 + ((64 + lg * 16) ^ sw16)];
    };
    auto rdB = [&](int ni, int base) {
        b[ni][0] = *(const i32x4*)&Bs[base + brow + ni * 2048 + ((lg * 16) ^ sw16)];
        b[ni][1] = *(const i32x4*)&Bs[base + brow + ni * 2048 + ((64 + lg * 16) ^ sw16)];
    };

    // ---- prologue: tile0 A+B, tile1 A; drain tile0, keep tile1-A in flight
    stage_half(0, 0, 0, 0);  stage_half(0, 1, 0, 0);
    stage_half(0, 0, 1, 0);  stage_half(0, 1, 1, 0);
    stage_half(1, 0, 0, BK); stage_half(1, 1, 0, BK);
    asm volatile("s_waitcnt vmcnt(4)" ::: "memory");
    __builtin_amdgcn_sched_barrier(0);
    __builtin_amdgcn_s_barrier();
    __builtin_amdgcn_sched_barrier(0);

    for (int t = 0; t < NT; ++t) {
        const int buf  = t & 1;
        const int base = buf * 32768;
        const int bufn = buf ^ 1;

        // ---- P1: reads for QUAD(0,0); stage B(t+1) h0; compute
        rdA(0, base); rdA(1, base); rdA(2, base); rdA(3, base);
        rdB(0, base); rdB(1, base);
        if (t + 1 < NT) stage_half(bufn, 0, 1, (t + 1) * BK);
        QUAD(0, 0);
        __builtin_amdgcn_s_barrier();              // plain: de-burst only

        // ---- P2: reads for QUAD(0,2); stage B(t+1) h1; compute
        rdB(2, base); rdB(3, base);
        if (t + 1 < NT) stage_half(bufn, 1, 1, (t + 1) * BK);
        QUAD(0, 2);
        __builtin_amdgcn_s_barrier();              // plain: de-burst only

        // ---- P3: reads for QUAD(4,2); compute; FENCED As-protect barrier
        rdA(4, base); rdA(5, base); rdA(6, base); rdA(7, base);
        QUAD(4, 2);
        __builtin_amdgcn_sched_barrier(0);
        __builtin_amdgcn_s_barrier();              // all As[buf] reads done
        __builtin_amdgcn_sched_barrier(0);

        // ---- P4: stage A(t+2) into freed As[buf]; QUAD(4,0); counted vmcnt
        if (t + 2 < NT) {
            stage_half(buf, 0, 0, (t + 2) * BK);
            stage_half(buf, 1, 0, (t + 2) * BK);
        }
        QUAD(4, 0);
        if (t + 2 < NT) {
            asm volatile("s_waitcnt vmcnt(4)" ::: "memory");
        } else if (t + 1 < NT) {
            asm volatile("s_waitcnt vmcnt(0)" ::: "memory");
        }
        __builtin_amdgcn_sched_barrier(0);
        __builtin_amdgcn_s_barrier();              // staged halves visible
        __builtin_amdgcn_sched_barrier(0);
    }

    // ---- epilogue: out = acc * dx[row] * dw[col]; C/D col=lane&15, row=lg*4+j
    float dwc[4];
#pragma unroll
    for (int ni = 0; ni < 4; ++ni) dwc[ni] = dW[b_row0 + wn * 64 + ni * 16 + lr];

    float* Cp = C + (a_row0 + wm * 128) * (size_t)OUT_F + b_row0 + wn * 64;
#pragma unroll
    for (int mi = 0; mi < 8; ++mi) {
#pragma unroll
        for (int j = 0; j < 4; ++j) {
            const int r = mi * 16 + lg * 4 + j;
            const float dxr = dX[a_row0 + wm * 128 + r];
#pragma unroll
            for (int ni = 0; ni < 4; ++ni)
                Cp[(size_t)r * OUT_F + ni * 16 + lr] =
                    (float)acc[mi][ni][j] * dxr * dwc[ni];
        }
    }
}

extern "C" void kernel_launch(void* const* d_in, const int* in_sizes, int n_in,
                              void* d_out, int out_size, void* d_ws, size_t ws_size,
                              hipStream_t stream) {
    const float* x      = (const float*)d_in[0];
    const int*   tern   = (const int*)d_in[1];
    const float* scales = (const float*)d_in[2];

    signed char* xq = (signed char*)d_ws;
    signed char* wq = xq + (size_t)TOKENS * IN_F;
    float*       dx = (float*)(wq + (size_t)OUT_F * IN_F);
    float*       dw = dx + TOKENS;

    quant_x_kernel<<<TOKENS, 256, 0, stream>>>(x, xq, dx);
    quant_w_kernel<<<OUT_F, 256, 0, stream>>>(tern, scales, wq, dw);

    dim3 grid((TOKENS / BM) * (OUT_F / BN));   // 512
    gemm_i8_kernel<<<grid, 512, 0, stream>>>(xq, wq, dx, dw, (float*)d_out);
}